// Round 2
// baseline (257.524 us; speedup 1.0000x reference)
//
#include <hip/hip_runtime.h>
#include <math.h>

// Problem constants (fixed by the reference)
constexpr int Bn  = 32;
constexpr int Cn  = 256;
constexpr int Hn  = 64;
constexpr int Wn  = 64;
constexpr int HW  = Hn * Wn;        // 4096
constexpr int CHW = Cn * HW;        // 1048576
constexpr int HW4 = HW / 4;         // 1024 float4 per (b,c) plane
constexpr int NPOS = Bn * HW;       // 131072 spatial positions

// Fused-kernel tiling
constexpr int TR  = 16;             // tile rows per block
constexpr int HR  = TR + 6;         // 22 halo rows
constexpr int HC  = Wn + 6;         // 70 halo cols
constexpr int HCP = 72;             // padded LDS row stride (bank-friendly)

// -------------------------------------------------------------------------
// Kernel 1: channel-wise max + mean.
// 512 blocks x 512 threads (8 waves). Wave w reduces channels [32w, 32w+32)
// for 64 consecutive float4 spatial positions (1 KiB coalesced per load).
// 2 blocks/CU = 16 waves/CU; unroll-8 keeps ~128 KB/CU of loads in flight.
// -------------------------------------------------------------------------
__global__ __launch_bounds__(512) void reduce_k(const float* __restrict__ x,
                                                float* __restrict__ pmax,
                                                float* __restrict__ pavg) {
    __shared__ float4 smax[8][64];
    __shared__ float4 ssum[8][64];

    const int lane = threadIdx.x & 63;
    const int wv   = threadIdx.x >> 6;            // 0..7
    const int pg   = blockIdx.x;                  // 0..511 position-group
    const int b    = pg >> 4;                     // 16 groups per batch image
    const int sp4  = (pg & 15) * 64 + lane;       // float4 index in plane

    const float4* xp = (const float4*)x + (size_t)b * (CHW / 4)
                       + (size_t)(wv * 32) * HW4 + sp4;

    float4 mx = make_float4(-INFINITY, -INFINITY, -INFINITY, -INFINITY);
    float4 sm = make_float4(0.f, 0.f, 0.f, 0.f);

    #pragma unroll 8
    for (int c = 0; c < 32; ++c) {
        float4 v = xp[(size_t)c * HW4];
        mx.x = fmaxf(mx.x, v.x); mx.y = fmaxf(mx.y, v.y);
        mx.z = fmaxf(mx.z, v.z); mx.w = fmaxf(mx.w, v.w);
        sm.x += v.x; sm.y += v.y; sm.z += v.z; sm.w += v.w;
    }

    smax[wv][lane] = mx;
    ssum[wv][lane] = sm;
    __syncthreads();

    if (wv == 0) {
        float4 M = smax[0][lane];
        float4 S = ssum[0][lane];
        #pragma unroll
        for (int k = 1; k < 8; ++k) {
            float4 m2 = smax[k][lane];
            float4 s2 = ssum[k][lane];
            M.x = fmaxf(M.x, m2.x); M.y = fmaxf(M.y, m2.y);
            M.z = fmaxf(M.z, m2.z); M.w = fmaxf(M.w, m2.w);
            S.x += s2.x; S.y += s2.y; S.z += s2.z; S.w += s2.w;
        }
        const float inv = 1.0f / (float)Cn;
        float4 A = make_float4(S.x * inv, S.y * inv, S.z * inv, S.w * inv);
        const int gpos4 = b * HW4 + sp4;
        ((float4*)pmax)[gpos4] = M;
        ((float4*)pavg)[gpos4] = A;
    }
}

// -------------------------------------------------------------------------
// Kernel 2: fused 7x7 conv + sigmoid + broadcast multiply.
// Grid = 32 b x 4 row-tiles x 8 channel-groups = 1024 blocks x 256 threads.
// Phase A: stage zero-padded pooled halo (22x70) into LDS (no branches later).
// Phase B: each thread computes conv+sigmoid for 4 horizontally-consecutive
//          pixels (one float4-position) -> scale in registers.
// Phase C: stream 32 channels: out = x * scale, float4 coalesced.
// -------------------------------------------------------------------------
__global__ __launch_bounds__(256) void fused_k(const float* __restrict__ x,
                                               const float* __restrict__ pmax,
                                               const float* __restrict__ pavg,
                                               const float* __restrict__ w,
                                               float* __restrict__ out) {
    __shared__ float pm[HR * HCP];
    __shared__ float pa[HR * HCP];
    __shared__ float sw[98];

    const int t  = threadIdx.x;
    const int cg = blockIdx.x & 7;            // channel group (32 ch)
    const int rt = (blockIdx.x >> 3) & 3;     // row tile (16 rows)
    const int b  = blockIdx.x >> 5;           // batch
    const int r0 = rt * TR;

    if (t < 98) sw[t] = w[t];

    // Phase A: stage pooled halo with zero padding.
    for (int i = t; i < HR * HC; i += 256) {
        const int r  = i / HC;
        const int c  = i % HC;
        const int gr = r0 - 3 + r;
        const int gc = c - 3;
        float vm = 0.f, va = 0.f;
        if (gr >= 0 && gr < Hn && gc >= 0 && gc < Wn) {
            const int o = b * HW + gr * Wn + gc;
            vm = pmax[o];
            va = pavg[o];
        }
        pm[r * HCP + c] = vm;
        pa[r * HCP + c] = va;
    }
    __syncthreads();

    // Phase B: conv (cross-correlation, already zero-padded) + sigmoid.
    // Thread t owns float4-position t of the tile: row = t>>4, cols 4*(t&15)..+3.
    const int prow = t >> 4;
    const int pcol = (t & 15) * 4;

    float4 acc = make_float4(0.f, 0.f, 0.f, 0.f);
    #pragma unroll
    for (int kh = 0; kh < 7; ++kh) {
        // halo row index for tap kh: (prow + kh); halo col index: pcol + kw + j
        const float* rm = &pm[(prow + kh) * HCP + pcol];
        const float* ra = &pa[(prow + kh) * HCP + pcol];
        float wm_[10], wa_[10];
        #pragma unroll
        for (int i2 = 0; i2 < 10; ++i2) { wm_[i2] = rm[i2]; wa_[i2] = ra[i2]; }
        #pragma unroll
        for (int kw = 0; kw < 7; ++kw) {
            const float cm = sw[kh * 7 + kw];
            const float ca = sw[49 + kh * 7 + kw];
            acc.x += wm_[kw    ] * cm + wa_[kw    ] * ca;
            acc.y += wm_[kw + 1] * cm + wa_[kw + 1] * ca;
            acc.z += wm_[kw + 2] * cm + wa_[kw + 2] * ca;
            acc.w += wm_[kw + 3] * cm + wa_[kw + 3] * ca;
        }
    }
    float4 s;
    s.x = 1.f / (1.f + expf(-acc.x));
    s.y = 1.f / (1.f + expf(-acc.y));
    s.z = 1.f / (1.f + expf(-acc.z));
    s.w = 1.f / (1.f + expf(-acc.w));

    // Phase C: multiply 32 channels of x by the tile's scale.
    const size_t base4 = (size_t)(b * Cn + cg * 32) * HW4 + (size_t)r0 * 16 + t;
    const float4* xb = (const float4*)x + base4;
    float4*       ob = (float4*)out + base4;

    #pragma unroll 8
    for (int c = 0; c < 32; ++c) {
        float4 v = xb[(size_t)c * HW4];
        v.x *= s.x; v.y *= s.y; v.z *= s.z; v.w *= s.w;
        ob[(size_t)c * HW4] = v;
    }
}

extern "C" void kernel_launch(void* const* d_in, const int* in_sizes, int n_in,
                              void* d_out, int out_size, void* d_ws, size_t ws_size,
                              hipStream_t stream) {
    const float* x = (const float*)d_in[0];
    const float* w = (const float*)d_in[1];
    float* out = (float*)d_out;

    // Workspace (floats): pmax[NPOS] | pavg[NPOS]  = 1 MB
    float* pmax = (float*)d_ws;
    float* pavg = pmax + NPOS;

    reduce_k<<<512, 512, 0, stream>>>(x, pmax, pavg);
    fused_k<<<1024, 256, 0, stream>>>(x, pmax, pavg, w, out);
}

// Round 4
// 256.950 us; speedup vs baseline: 1.0022x; 1.0022x over previous
//
#include <hip/hip_runtime.h>
#include <math.h>

// Problem constants (fixed by the reference)
constexpr int Bn  = 32;
constexpr int Cn  = 256;
constexpr int Hn  = 64;
constexpr int Wn  = 64;
constexpr int HW  = Hn * Wn;        // 4096
constexpr int CHW = Cn * HW;        // 1048576
constexpr int HW4 = HW / 4;         // 1024 float4 per (b,c) plane
constexpr int NPOS = Bn * HW;       // 131072 spatial positions

// Fused-kernel tiling
constexpr int TR  = 16;             // tile rows per block
constexpr int HR  = TR + 6;         // 22 halo rows
constexpr int HC  = Wn + 6;         // 70 halo cols
constexpr int HCP = 72;             // padded LDS row stride

// -------------------------------------------------------------------------
// Kernel 1: channel-wise max + mean.
// 512 blocks x 512 threads (8 waves). Wave w reduces channels [32w, 32w+32)
// for 64 consecutive float4 spatial positions (1 KiB coalesced per load).
// Regular caching loads on purpose: x (128 MiB) read-allocates into the
// 256 MiB L3; x + out together fit, so fused_k's re-read stays L3-served.
// -------------------------------------------------------------------------
__global__ __launch_bounds__(512) void reduce_k(const float* __restrict__ x,
                                                float* __restrict__ pmax,
                                                float* __restrict__ pavg) {
    __shared__ float4 smax[8][64];
    __shared__ float4 ssum[8][64];

    const int lane = threadIdx.x & 63;
    const int wv   = threadIdx.x >> 6;            // 0..7
    const int pg   = blockIdx.x;                  // 0..511 position-group
    const int b    = pg >> 4;                     // 16 groups per batch image
    const int sp4  = (pg & 15) * 64 + lane;       // float4 index in plane

    const float4* xp = (const float4*)x + (size_t)b * (CHW / 4)
                       + (size_t)(wv * 32) * HW4 + sp4;

    float4 mx = make_float4(-INFINITY, -INFINITY, -INFINITY, -INFINITY);
    float4 sm = make_float4(0.f, 0.f, 0.f, 0.f);

    #pragma unroll 8
    for (int c = 0; c < 32; ++c) {
        float4 v = xp[(size_t)c * HW4];
        mx.x = fmaxf(mx.x, v.x); mx.y = fmaxf(mx.y, v.y);
        mx.z = fmaxf(mx.z, v.z); mx.w = fmaxf(mx.w, v.w);
        sm.x += v.x; sm.y += v.y; sm.z += v.z; sm.w += v.w;
    }

    smax[wv][lane] = mx;
    ssum[wv][lane] = sm;
    __syncthreads();

    if (wv == 0) {
        float4 M = smax[0][lane];
        float4 S = ssum[0][lane];
        #pragma unroll
        for (int k = 1; k < 8; ++k) {
            float4 m2 = smax[k][lane];
            float4 s2 = ssum[k][lane];
            M.x = fmaxf(M.x, m2.x); M.y = fmaxf(M.y, m2.y);
            M.z = fmaxf(M.z, m2.z); M.w = fmaxf(M.w, m2.w);
            S.x += s2.x; S.y += s2.y; S.z += s2.z; S.w += s2.w;
        }
        const float inv = 1.0f / (float)Cn;
        float4 A = make_float4(S.x * inv, S.y * inv, S.z * inv, S.w * inv);
        const int gpos4 = b * HW4 + sp4;
        ((float4*)pmax)[gpos4] = M;
        ((float4*)pavg)[gpos4] = A;
    }
}

// -------------------------------------------------------------------------
// Kernel 2: fused 7x7 conv + sigmoid + broadcast multiply.
// Grid = 32 b x 4 row-tiles x 8 channel-groups = 1024 blocks x 256 threads.
// Phase A: stage zero-padded pooled halo (22x70) into LDS.
// Phase B: conv + sigmoid for 4 consecutive pixels per thread -> registers.
// Phase C: stream 32 channels: out = x * scale, float4 coalesced.
// NOTE: plain stores only. Nontemporal stores to d_out corrupt results here:
// the harness's 0xAA poison sits dirty in L2 and, with nt stores bypassing
// L2, those poison lines evict later and clobber the output (round-3 fail).
// -------------------------------------------------------------------------
__global__ __launch_bounds__(256) void fused_k(const float* __restrict__ x,
                                               const float* __restrict__ pmax,
                                               const float* __restrict__ pavg,
                                               const float* __restrict__ w,
                                               float* __restrict__ out) {
    __shared__ float pm[HR * HCP];
    __shared__ float pa[HR * HCP];
    __shared__ float sw[98];

    const int t  = threadIdx.x;
    const int cg = blockIdx.x & 7;            // channel group (32 ch)
    const int rt = (blockIdx.x >> 3) & 3;     // row tile (16 rows)
    const int b  = blockIdx.x >> 5;           // batch
    const int r0 = rt * TR;

    if (t < 98) sw[t] = w[t];

    // Phase A: stage pooled halo with zero padding.
    for (int i = t; i < HR * HC; i += 256) {
        const int r  = i / HC;
        const int c  = i % HC;
        const int gr = r0 - 3 + r;
        const int gc = c - 3;
        float vm = 0.f, va = 0.f;
        if (gr >= 0 && gr < Hn && gc >= 0 && gc < Wn) {
            const int o = b * HW + gr * Wn + gc;
            vm = pmax[o];
            va = pavg[o];
        }
        pm[r * HCP + c] = vm;
        pa[r * HCP + c] = va;
    }
    __syncthreads();

    // Phase B: conv (zero-padded in LDS, no branches) + sigmoid.
    const int prow = t >> 4;
    const int pcol = (t & 15) * 4;

    float4 acc = make_float4(0.f, 0.f, 0.f, 0.f);
    #pragma unroll
    for (int kh = 0; kh < 7; ++kh) {
        const float* rm = &pm[(prow + kh) * HCP + pcol];
        const float* ra = &pa[(prow + kh) * HCP + pcol];
        float wm_[10], wa_[10];
        #pragma unroll
        for (int i2 = 0; i2 < 10; ++i2) { wm_[i2] = rm[i2]; wa_[i2] = ra[i2]; }
        #pragma unroll
        for (int kw = 0; kw < 7; ++kw) {
            const float cm = sw[kh * 7 + kw];
            const float ca = sw[49 + kh * 7 + kw];
            acc.x += wm_[kw    ] * cm + wa_[kw    ] * ca;
            acc.y += wm_[kw + 1] * cm + wa_[kw + 1] * ca;
            acc.z += wm_[kw + 2] * cm + wa_[kw + 2] * ca;
            acc.w += wm_[kw + 3] * cm + wa_[kw + 3] * ca;
        }
    }
    float4 s;
    s.x = 1.f / (1.f + expf(-acc.x));
    s.y = 1.f / (1.f + expf(-acc.y));
    s.z = 1.f / (1.f + expf(-acc.z));
    s.w = 1.f / (1.f + expf(-acc.w));

    // Phase C: multiply 32 channels of x by the tile's scale.
    const size_t base4 = (size_t)(b * Cn + cg * 32) * HW4 + (size_t)r0 * 16 + t;
    const float4* xb = (const float4*)x + base4;
    float4*       ob = (float4*)out + base4;

    #pragma unroll 8
    for (int c = 0; c < 32; ++c) {
        float4 v = xb[(size_t)c * HW4];
        v.x *= s.x; v.y *= s.y; v.z *= s.z; v.w *= s.w;
        ob[(size_t)c * HW4] = v;
    }
}

extern "C" void kernel_launch(void* const* d_in, const int* in_sizes, int n_in,
                              void* d_out, int out_size, void* d_ws, size_t ws_size,
                              hipStream_t stream) {
    const float* x = (const float*)d_in[0];
    const float* w = (const float*)d_in[1];
    float* out = (float*)d_out;

    // Workspace (floats): pmax[NPOS] | pavg[NPOS]  = 1 MB
    float* pmax = (float*)d_ws;
    float* pavg = pmax + NPOS;

    reduce_k<<<512, 512, 0, stream>>>(x, pmax, pavg);
    fused_k<<<1024, 256, 0, stream>>>(x, pmax, pavg, w, out);
}